// Round 1
// baseline (1337.183 us; speedup 1.0000x reference)
//
#include <hip/hip_runtime.h>

// MassConservingLSTMCell — fused f32 implementation (round 0: correctness + baseline).
// B=1024 batches, U=256 units, F=31 extra features, D=1+U+F=288 feature dim.
//
// Pipeline:
//   K0: memset cell_sys accumulator (ws) to zero
//   K1a: features: featT[k][b] = [p, last_cell/L1, other]  (k-major, 288x1024)
//   K1b: gates: ig_n, og  -> stashed in d_out (overwritten by K3)
//   K2 : heavy fused GEMM: for each u: C = feat @ W_r[:, u*256:(u+1)*256] + b_r,
//        relu, rowsum over v, scale by last_cell[b,u]/rowsum, accumulate -> atomicAdd
//   K3 : finalize: candidate = ig_n*p + cell_sys; out = og*cand; cell = (1-og)*cand

#define EPS_L1 1e-7f

constexpr int B = 1024;
constexpr int U = 256;
constexpr int F = 31;
constexpr int D = 1 + U + F;     // 288
constexpr int NBV = B * U;       // 262144
constexpr int UU = U * U;        // 65536

// ---------------------------------------------------------------- K1a: features
__global__ __launch_bounds__(256) void k_features(
    const float* __restrict__ lc, const float* __restrict__ p,
    const float* __restrict__ other, float* __restrict__ featT) {
  const int b = blockIdx.x;
  const int t = threadIdx.x;
  const float v = lc[b * U + t];
  float a = fabsf(v);
#pragma unroll
  for (int m = 1; m < 64; m <<= 1) a += __shfl_xor(a, m, 64);
  __shared__ float red[4];
  const int lane = t & 63, wv = t >> 6;
  if (lane == 0) red[wv] = a;
  __syncthreads();
  const float l1 = red[0] + red[1] + red[2] + red[3] + EPS_L1;
  featT[(1 + t) * B + b] = v / l1;
  if (t == 0) featT[b] = p[b];
  if (t < F) featT[(1 + U + t) * B + b] = other[b * F + t];
}

// ---------------------------------------------------------------- K1b: gates
// 64 blocks x 256 threads; each block handles 16 batch rows, thread t = unit column.
__global__ __launch_bounds__(256) void k_gates(
    const float* __restrict__ featT,
    const float* __restrict__ Wi, const float* __restrict__ bi,
    const float* __restrict__ Wo, const float* __restrict__ bo,
    float* __restrict__ ig_n, float* __restrict__ og) {
  constexpr int RB = 16;
  __shared__ float fT[D * RB];      // [k][r], stride 16 floats (64B -> b128 ok)
  __shared__ float redb[RB * 4];
  __shared__ float sums[RB];
  const int t = threadIdx.x;
  const int b0 = blockIdx.x * RB;

  for (int i = t; i < D * RB; i += 256) {
    const int k = i >> 4, r = i & 15;
    fT[i] = featT[k * B + b0 + r];
  }
  __syncthreads();

  float ai[RB], ao[RB];
  const float bit = bi[t], bot = bo[t];
#pragma unroll
  for (int r = 0; r < RB; ++r) { ai[r] = bit; ao[r] = bot; }

  for (int k = 0; k < D; ++k) {
    const float wi = Wi[k * U + t];
    const float wo = Wo[k * U + t];
    const float4* fp = (const float4*)(&fT[k * RB]);
#pragma unroll
    for (int q = 0; q < 4; ++q) {
      const float4 f = fp[q];
      const float fr[4] = {f.x, f.y, f.z, f.w};
#pragma unroll
      for (int j = 0; j < 4; ++j) {
        ai[4 * q + j] = fmaf(fr[j], wi, ai[4 * q + j]);
        ao[4 * q + j] = fmaf(fr[j], wo, ao[4 * q + j]);
      }
    }
  }

  float ig[RB], s[RB];
#pragma unroll
  for (int r = 0; r < RB; ++r) {
    ig[r] = 1.0f / (1.0f + expf(-ai[r]));
    s[r] = ig[r];                       // ig > 0, so |ig| == ig
  }
#pragma unroll
  for (int m = 1; m < 64; m <<= 1) {
#pragma unroll
    for (int r = 0; r < RB; ++r) s[r] += __shfl_xor(s[r], m, 64);
  }
  const int lane = t & 63, wv = t >> 6;
  if (lane == 0) {
#pragma unroll
    for (int r = 0; r < RB; ++r) redb[r * 4 + wv] = s[r];
  }
  __syncthreads();
  if (t < RB) sums[t] = redb[t * 4] + redb[t * 4 + 1] + redb[t * 4 + 2] + redb[t * 4 + 3];
  __syncthreads();
#pragma unroll
  for (int r = 0; r < RB; ++r) {
    ig_n[(b0 + r) * U + t] = ig[r] / sums[r];
    og[(b0 + r) * U + t]   = 1.0f / (1.0f + expf(-ao[r]));
  }
}

// ---------------------------------------------------------------- K2: heavy fused GEMM
// grid (16 Mblocks, 16 Ugroups), 256 threads. Block: 64 rows x 16 u's.
// Thread tile: 8 rows x 8 cols. tv = t&31 (cols 8*tv..8*tv+7), tr = t>>5 (rows 8*tr..).
__global__ __launch_bounds__(256, 2) void k_heavy(
    const float* __restrict__ featT, const float* __restrict__ lc,
    const float* __restrict__ Wr, const float* __restrict__ br,
    float* __restrict__ cell_sys) {
  constexpr int MT = 64;
  constexpr int UG = 16;
  __shared__ float fT[D * MT];      // [k][r], 288*64*4 = 73728 B (reads are broadcasts)
  __shared__ float rowsum_s[MT];
  __shared__ float alpha_s[MT];

  const int t  = threadIdx.x;
  const int tv = t & 31;
  const int tr = t >> 5;
  const int b0 = blockIdx.x * MT;
  const int u0 = blockIdx.y * UG;

  for (int i = t; i < D * MT; i += 256) {
    const int k = i >> 6, r = i & 63;
    fT[i] = featT[k * B + b0 + r];
  }
  __syncthreads();

  float out[8][8];
#pragma unroll
  for (int j = 0; j < 8; ++j)
#pragma unroll
    for (int i = 0; i < 8; ++i) out[j][i] = 0.0f;

  const float* Fbase = &fT[tr * 8];

  for (int uu = 0; uu < UG; ++uu) {
    const int u = u0 + uu;
    const float* Wbase = Wr + (size_t)u * 256 + tv * 8;

    float c[8][8];
#pragma unroll
    for (int j = 0; j < 8; ++j)
#pragma unroll
      for (int i = 0; i < 8; ++i) c[j][i] = 0.0f;

    // software-pipelined k-loop: W prefetch distance 2, feature prefetch distance 1
    float4 wa, wb, wa1, wb1, wa2, wb2, fa, fb, fa1, fb1;
    {
      const float4* wp0 = (const float4*)(Wbase);
      wa = wp0[0]; wb = wp0[1];
      const float4* wp1 = (const float4*)(Wbase + (size_t)UU);
      wa1 = wp1[0]; wb1 = wp1[1];
      const float4* fp0 = (const float4*)(Fbase);
      fa = fp0[0]; fb = fp0[1];
    }
#pragma unroll 2
    for (int k = 0; k < D; ++k) {
      const int kw = (k + 2 < D) ? k + 2 : D - 1;
      const int kf = (k + 1 < D) ? k + 1 : D - 1;
      const float4* wp = (const float4*)(Wbase + (size_t)kw * UU);
      wa2 = wp[0]; wb2 = wp[1];
      const float4* fp = (const float4*)(Fbase + kf * MT);
      fa1 = fp[0]; fb1 = fp[1];

      const float fr[8] = {fa.x, fa.y, fa.z, fa.w, fb.x, fb.y, fb.z, fb.w};
      const float wc[8] = {wa.x, wa.y, wa.z, wa.w, wb.x, wb.y, wb.z, wb.w};
#pragma unroll
      for (int j = 0; j < 8; ++j)
#pragma unroll
        for (int i = 0; i < 8; ++i)
          c[j][i] = fmaf(fr[j], wc[i], c[j][i]);

      wa = wa1; wb = wb1; wa1 = wa2; wb1 = wb2;
      fa = fa1; fb = fb1;
    }

    // bias + relu + per-thread partial rowsums
    const float4* bp = (const float4*)(br + (size_t)u * 256 + tv * 8);
    const float4 bb0 = bp[0], bb1 = bp[1];
    const float bc[8] = {bb0.x, bb0.y, bb0.z, bb0.w, bb1.x, bb1.y, bb1.z, bb1.w};
    float ps[8];
#pragma unroll
    for (int j = 0; j < 8; ++j) {
      float s = 0.0f;
#pragma unroll
      for (int i = 0; i < 8; ++i) {
        c[j][i] = fmaxf(c[j][i] + bc[i], 0.0f);
        s += c[j][i];
      }
      ps[j] = s;
    }
    // reduce over the 32 tv-groups (xor masks 1..16 stay within the half-wave)
#pragma unroll
    for (int m = 1; m < 32; m <<= 1) {
#pragma unroll
      for (int j = 0; j < 8; ++j) ps[j] += __shfl_xor(ps[j], m, 64);
    }
    if (tv == 0) {
#pragma unroll
      for (int j = 0; j < 8; ++j) rowsum_s[tr * 8 + j] = ps[j];
    }
    __syncthreads();
    if (t < MT) alpha_s[t] = lc[(b0 + t) * U + u] / rowsum_s[t];
    __syncthreads();
#pragma unroll
    for (int j = 0; j < 8; ++j) {
      const float a = alpha_s[tr * 8 + j];
#pragma unroll
      for (int i = 0; i < 8; ++i) out[j][i] = fmaf(a, c[j][i], out[j][i]);
    }
  }

#pragma unroll
  for (int j = 0; j < 8; ++j) {
    const int row = b0 + tr * 8 + j;
#pragma unroll
    for (int i = 0; i < 8; ++i)
      atomicAdd(&cell_sys[row * U + tv * 8 + i], out[j][i]);
  }
}

// ---------------------------------------------------------------- K3: finalize
__global__ __launch_bounds__(256) void k_final(
    const float* __restrict__ cell_sys, const float* __restrict__ p,
    float* __restrict__ d_out) {
  const int i = blockIdx.x * 256 + threadIdx.x;   // grid 1024 -> covers NBV
  const float ig = d_out[i];          // ig_n stashed in d_out[0:NBV)
  const float ogv = d_out[NBV + i];   // og stashed in d_out[NBV:2NBV)
  const float cand = fmaf(ig, p[i >> 8], cell_sys[i]);
  const float outp = ogv * cand;
  d_out[i] = (1.0f - ogv) * cand;
  d_out[NBV + i] = outp;
}

// ---------------------------------------------------------------- launch
extern "C" void kernel_launch(void* const* d_in, const int* in_sizes, int n_in,
                              void* d_out, int out_size, void* d_ws, size_t ws_size,
                              hipStream_t stream) {
  const float* lc    = (const float*)d_in[0];
  const float* p     = (const float*)d_in[1];
  const float* other = (const float*)d_in[2];
  const float* Wi    = (const float*)d_in[3];
  const float* bi    = (const float*)d_in[4];
  const float* Wr    = (const float*)d_in[5];
  const float* br    = (const float*)d_in[6];
  const float* Wo    = (const float*)d_in[7];
  const float* bo    = (const float*)d_in[8];

  float* out = (float*)d_out;
  float* wsf = (float*)d_ws;
  float* featT    = wsf;                 // 288*1024 floats = 1.125 MiB
  float* cell_sys = wsf + D * B;         // 1024*256 floats = 1 MiB

  float* ig_n = out;                     // stash gates in d_out; K3 overwrites
  float* og   = out + NBV;

  hipMemsetAsync(cell_sys, 0, (size_t)NBV * sizeof(float), stream);
  k_features<<<B, 256, 0, stream>>>(lc, p, other, featT);
  k_gates<<<B / 16, 256, 0, stream>>>(featT, Wi, bi, Wo, bo, ig_n, og);
  k_heavy<<<dim3(16, 16), 256, 0, stream>>>(featT, lc, Wr, br, cell_sys);
  k_final<<<B, 256, 0, stream>>>(cell_sys, p, out);
}

// Round 2
// 247.783 us; speedup vs baseline: 5.3966x; 5.3966x over previous
//
#include <hip/hip_runtime.h>

// MassConservingLSTMCell — round 2: bf16 MFMA for the heavy einsum + gates.
// B=1024, U=256, F=31, D=288 (= 9 k-chunks of 32).
//
// Fast path (needs ~39.7 MB ws):
//   k_wt       : W_r/W_i/W_o f32 -> bf16, pre-swizzled into per-(u,c) 16KB LDS images
//   k_features : features -> bf16 row-major [b][288]
//   k_gatesM   : MFMA gates -> ig_n, og stashed in d_out
//   k_heavyM   : MFMA fused R-GEMM + relu + row-norm + lc-weighted accumulate (atomics)
//   k_final    : combine
// Fallback (small ws): round-0 f32 path (verified correct @1337us).

#define EPS_L1 1e-7f

constexpr int B = 1024;
constexpr int U = 256;
constexpr int F = 31;
constexpr int D = 1 + U + F;     // 288
constexpr int NBV = B * U;       // 262144
constexpr int UU = U * U;        // 65536
constexpr int NCH = D / 32;      // 9 k-chunks
constexpr int CHB = 16384;       // bytes per (u, chunk) B-image: 256 v * 32 k * 2B
constexpr int UIMG = NCH * CHB;  // 147456 B per u-slice image
constexpr int ROWB = D * 2;      // 576 bytes per bf16 feature row

typedef float f32x4 __attribute__((ext_vector_type(4)));
typedef short bf16x8 __attribute__((ext_vector_type(8)));

__device__ __forceinline__ unsigned short f2bf(float x) {
  union { float f; unsigned u; } v; v.f = x;
  unsigned r = v.u + 0x7FFFu + ((v.u >> 16) & 1u);
  return (unsigned short)(r >> 16);
}

#define GLDS16(gp, lp)                                                        \
  __builtin_amdgcn_global_load_lds(                                          \
      (const __attribute__((address_space(1))) void*)(gp),                   \
      (__attribute__((address_space(3))) void*)(lp), 16, 0, 0)

// ---------------------------------------------------------------- k_wt
// Build bf16 fragment-layout images. Image element (u, c, n0, lane, j) holds
// W[k = c*32 + (lane>>4)*8 + j][col v = n0*16 + (lane&15)] so that a linear
// global_load_lds + ds_read_b128 at lane*16 yields the B-fragment directly.
__global__ __launch_bounds__(256) void k_wt(
    const float* __restrict__ Wr, const float* __restrict__ Wi,
    const float* __restrict__ Wo, short* __restrict__ WtB) {
  const int u = blockIdx.x >> 2;
  const int q = blockIdx.x & 3;
  const int t = threadIdx.x, lane = t & 63, wave = t >> 6;
  const int g = lane >> 4, v_ = lane & 15;

  const float* src; long ld;
  if (u < 256)      { src = Wr + (size_t)u * 256; ld = UU; }
  else if (u == 256){ src = Wi; ld = 256; }
  else              { src = Wo; ld = 256; }
  short* dst = WtB + (size_t)u * (UIMG / 2);

#pragma unroll
  for (int i = 0; i < 9; ++i) {
    const int r = q * 36 + wave * 9 + i;         // region 0..143
    const int c = r >> 4, n0 = r & 15;
    const float* ps = src + (size_t)(c * 32 + g * 8) * ld + n0 * 16 + v_;
    bf16x8 h;
#pragma unroll
    for (int j = 0; j < 8; ++j) h[j] = (short)f2bf(ps[(size_t)j * ld]);
    *(bf16x8*)(dst + (size_t)r * 512 + lane * 8) = h;
  }
}

// ---------------------------------------------------------------- k_features (bf16)
__global__ __launch_bounds__(256) void k_featB(
    const float* __restrict__ lc, const float* __restrict__ p,
    const float* __restrict__ other, short* __restrict__ featB) {
  const int b = blockIdx.x;
  const int t = threadIdx.x;
  const float v = lc[b * U + t];
  float a = fabsf(v);
#pragma unroll
  for (int m = 1; m < 64; m <<= 1) a += __shfl_xor(a, m, 64);
  __shared__ float red[4];
  const int lane = t & 63, wv = t >> 6;
  if (lane == 0) red[wv] = a;
  __syncthreads();
  const float l1 = red[0] + red[1] + red[2] + red[3] + EPS_L1;
  short* row = featB + (size_t)b * D;
  row[1 + t] = (short)f2bf(v / l1);
  if (t == 0) row[0] = (short)f2bf(p[b]);
  if (t < F) row[1 + U + t] = (short)f2bf(other[b * F + t]);
}

// ---------------------------------------------------------------- MFMA kernels
// Block frame: 64 rows x 256 cols, 4 waves. wave: rowhalf=wave>>1 (32 rows),
// colhalf=wave&1 (128 cols). Per wave: 2 m-tiles x 8 n-tiles of 16x16.

__global__ __launch_bounds__(256, 2) void k_heavyM(
    const short* __restrict__ featB, const short* __restrict__ WtB,
    const float* __restrict__ lc, const float* __restrict__ br,
    float* __restrict__ cell_sys) {
  __shared__ short aT[18432];          // 64 rows x 576B = 36864B
  __shared__ short bT2[2][8192];       // 2 x 16KB B chunk
  __shared__ float rsum[2][64];
  __shared__ float lcs[64];

  const int t = threadIdx.x, lane = t & 63, wave = t >> 6;
  const int colhalf = wave & 1, r0 = (wave >> 1) * 32;
  const int b0 = blockIdx.x * 64;
  const int u0 = blockIdx.y * 8;       // 8 u's per block

  // stage A (36864 B, linear)
  {
    const char* gsrc = (const char*)featB + (size_t)b0 * ROWB + t * 16;
    char* lbase = (char*)aT + wave * 1024;
#pragma unroll
    for (int p2 = 0; p2 < 9; ++p2) GLDS16(gsrc + p2 * 4096, lbase + p2 * 4096);
  }

  f32x4 acc[2][8], outa[2][8];
#pragma unroll
  for (int mt = 0; mt < 2; ++mt)
#pragma unroll
    for (int n = 0; n < 8; ++n)
#pragma unroll
      for (int r = 0; r < 4; ++r) { acc[mt][n][r] = 0.f; outa[mt][n][r] = 0.f; }

  const char* wbase = (const char*)WtB + ((size_t)u0 * NCH) * CHB;
  auto stage_b = [&](int s, int buf) {
    const char* gsrc = wbase + ((size_t)s << 14) + t * 16;
    char* lbase = (char*)bT2[buf] + wave * 1024;
#pragma unroll
    for (int p2 = 0; p2 < 4; ++p2) GLDS16(gsrc + p2 * 4096, lbase + p2 * 4096);
  };

  stage_b(0, 0);
  int c = 0, uu = 0;
  const int quad = lane >> 4, l15 = lane & 15;

  for (int s = 0; s < 8 * NCH; ++s) {
    __syncthreads();                       // drains stage(s); guards buf reuse
    if (s + 1 < 8 * NCH) stage_b(s + 1, (s + 1) & 1);

    const char* ab = (const char*)aT + c * 64 + quad * 16;
    const bf16x8 af0 = *(const bf16x8*)(ab + (size_t)(r0 + l15) * ROWB);
    const bf16x8 af1 = *(const bf16x8*)(ab + (size_t)(r0 + 16 + l15) * ROWB);
    const char* bb = (const char*)bT2[s & 1] + lane * 16 + colhalf * 8192;
#pragma unroll
    for (int n = 0; n < 8; ++n) {
      const bf16x8 bf = *(const bf16x8*)(bb + (n << 10));
      acc[0][n] = __builtin_amdgcn_mfma_f32_16x16x32_bf16(af0, bf, acc[0][n], 0, 0, 0);
      acc[1][n] = __builtin_amdgcn_mfma_f32_16x16x32_bf16(af1, bf, acc[1][n], 0, 0, 0);
    }

    if (c == 8) {
      // ---- epilogue for u = u0+uu: bias+relu+rownorm+weighted accumulate
      const int ug = u0 + uu;
      if (t < 64) lcs[t] = lc[(size_t)(b0 + t) * U + ug];
      float bv[8];
#pragma unroll
      for (int n = 0; n < 8; ++n)
        bv[n] = br[(size_t)ug * U + colhalf * 128 + n * 16 + l15];
      float sm[2][4];
#pragma unroll
      for (int mt = 0; mt < 2; ++mt)
#pragma unroll
        for (int r = 0; r < 4; ++r) {
          float sv = 0.f;
#pragma unroll
          for (int n = 0; n < 8; ++n) sv += fmaxf(acc[mt][n][r] + bv[n], 0.f);
          sm[mt][r] = sv;
        }
#pragma unroll
      for (int m = 1; m < 16; m <<= 1)
#pragma unroll
        for (int mt = 0; mt < 2; ++mt)
#pragma unroll
          for (int r = 0; r < 4; ++r) sm[mt][r] += __shfl_xor(sm[mt][r], m, 64);
      if (l15 == 0) {
#pragma unroll
        for (int mt = 0; mt < 2; ++mt)
#pragma unroll
          for (int r = 0; r < 4; ++r)
            rsum[colhalf][r0 + mt * 16 + quad * 4 + r] = sm[mt][r];
      }
      __syncthreads();
#pragma unroll
      for (int mt = 0; mt < 2; ++mt)
#pragma unroll
        for (int r = 0; r < 4; ++r) {
          const int row = r0 + mt * 16 + quad * 4 + r;
          const float alpha = lcs[row] / (rsum[0][row] + rsum[1][row]);
#pragma unroll
          for (int n = 0; n < 8; ++n) {
            outa[mt][n][r] = fmaf(alpha, fmaxf(acc[mt][n][r] + bv[n], 0.f), outa[mt][n][r]);
            acc[mt][n][r] = 0.f;
          }
        }
      c = 0; ++uu;
    } else {
      ++c;
    }
  }

#pragma unroll
  for (int mt = 0; mt < 2; ++mt)
#pragma unroll
    for (int r = 0; r < 4; ++r) {
      const int row = b0 + r0 + mt * 16 + quad * 4 + r;
#pragma unroll
      for (int n = 0; n < 8; ++n)
        atomicAdd(&cell_sys[(size_t)row * U + colhalf * 128 + n * 16 + l15],
                  outa[mt][n][r]);
    }
}

// Gates: same frame, 16 blocks, u-images 256 (Wi) and 257 (Wo).
__global__ __launch_bounds__(256, 2) void k_gatesM(
    const short* __restrict__ featB, const short* __restrict__ WtB,
    const float* __restrict__ bi, const float* __restrict__ bo,
    float* __restrict__ dout) {
  __shared__ short aT[18432];
  __shared__ short bT2[2][8192];
  __shared__ float rsum[2][64];

  const int t = threadIdx.x, lane = t & 63, wave = t >> 6;
  const int colhalf = wave & 1, r0 = (wave >> 1) * 32;
  const int b0 = blockIdx.x * 64;
  const int quad = lane >> 4, l15 = lane & 15;

  {
    const char* gsrc = (const char*)featB + (size_t)b0 * ROWB + t * 16;
    char* lbase = (char*)aT + wave * 1024;
#pragma unroll
    for (int p2 = 0; p2 < 9; ++p2) GLDS16(gsrc + p2 * 4096, lbase + p2 * 4096);
  }

  f32x4 acc[2][8];
#pragma unroll
  for (int mt = 0; mt < 2; ++mt)
#pragma unroll
    for (int n = 0; n < 8; ++n)
#pragma unroll
      for (int r = 0; r < 4; ++r) acc[mt][n][r] = 0.f;

  const char* wbase = (const char*)WtB + (size_t)256 * UIMG;
  auto stage_b = [&](int s, int buf) {
    const char* gsrc = wbase + ((size_t)s << 14) + t * 16;
    char* lbase = (char*)bT2[buf] + wave * 1024;
#pragma unroll
    for (int p2 = 0; p2 < 4; ++p2) GLDS16(gsrc + p2 * 4096, lbase + p2 * 4096);
  };

  stage_b(0, 0);
  int c = 0, g = 0;
  for (int s = 0; s < 2 * NCH; ++s) {
    __syncthreads();
    if (s + 1 < 2 * NCH) stage_b(s + 1, (s + 1) & 1);

    const char* ab = (const char*)aT + c * 64 + quad * 16;
    const bf16x8 af0 = *(const bf16x8*)(ab + (size_t)(r0 + l15) * ROWB);
    const bf16x8 af1 = *(const bf16x8*)(ab + (size_t)(r0 + 16 + l15) * ROWB);
    const char* bb = (const char*)bT2[s & 1] + lane * 16 + colhalf * 8192;
#pragma unroll
    for (int n = 0; n < 8; ++n) {
      const bf16x8 bf = *(const bf16x8*)(bb + (n << 10));
      acc[0][n] = __builtin_amdgcn_mfma_f32_16x16x32_bf16(af0, bf, acc[0][n], 0, 0, 0);
      acc[1][n] = __builtin_amdgcn_mfma_f32_16x16x32_bf16(af1, bf, acc[1][n], 0, 0, 0);
    }

    if (c == 8) {
      const float* bias = (g == 0) ? bi : bo;
      float bv[8];
#pragma unroll
      for (int n = 0; n < 8; ++n) bv[n] = bias[colhalf * 128 + n * 16 + l15];
      float vg[2][8][4];
#pragma unroll
      for (int mt = 0; mt < 2; ++mt)
#pragma unroll
        for (int n = 0; n < 8; ++n)
#pragma unroll
          for (int r = 0; r < 4; ++r) {
            vg[mt][n][r] = 1.f / (1.f + __expf(-(acc[mt][n][r] + bv[n])));
            acc[mt][n][r] = 0.f;
          }
      if (g == 0) {
        float sm[2][4];
#pragma unroll
        for (int mt = 0; mt < 2; ++mt)
#pragma unroll
          for (int r = 0; r < 4; ++r) {
            float sv = 0.f;
#pragma unroll
            for (int n = 0; n < 8; ++n) sv += vg[mt][n][r];
            sm[mt][r] = sv;
          }
#pragma unroll
        for (int m = 1; m < 16; m <<= 1)
#pragma unroll
          for (int mt = 0; mt < 2; ++mt)
#pragma unroll
            for (int r = 0; r < 4; ++r) sm[mt][r] += __shfl_xor(sm[mt][r], m, 64);
        if (l15 == 0)
#pragma unroll
          for (int mt = 0; mt < 2; ++mt)
#pragma unroll
            for (int r = 0; r < 4; ++r)
              rsum[colhalf][r0 + mt * 16 + quad * 4 + r] = sm[mt][r];
        __syncthreads();
#pragma unroll
        for (int mt = 0; mt < 2; ++mt)
#pragma unroll
          for (int r = 0; r < 4; ++r) {
            const int row = r0 + mt * 16 + quad * 4 + r;
            const float inv = 1.f / (rsum[0][row] + rsum[1][row]);
#pragma unroll
            for (int n = 0; n < 8; ++n)
              dout[(size_t)(b0 + row) * U + colhalf * 128 + n * 16 + l15] =
                  vg[mt][n][r] * inv;
          }
      } else {
#pragma unroll
        for (int mt = 0; mt < 2; ++mt)
#pragma unroll
          for (int r = 0; r < 4; ++r) {
            const int row = r0 + mt * 16 + quad * 4 + r;
#pragma unroll
            for (int n = 0; n < 8; ++n)
              dout[(size_t)NBV + (size_t)(b0 + row) * U + colhalf * 128 + n * 16 + l15] =
                  vg[mt][n][r];
          }
      }
      c = 0; ++g;
    } else {
      ++c;
    }
  }
}

// ---------------------------------------------------------------- k_final
__global__ __launch_bounds__(256) void k_final(
    const float* __restrict__ cell_sys, const float* __restrict__ p,
    float* __restrict__ d_out) {
  const int i = blockIdx.x * 256 + threadIdx.x;
  const float ig = d_out[i];
  const float ogv = d_out[NBV + i];
  const float cand = fmaf(ig, p[i >> 8], cell_sys[i]);
  const float outp = ogv * cand;
  d_out[i] = (1.0f - ogv) * cand;
  d_out[NBV + i] = outp;
}

// ================================================================ fallback (round-0 f32 path)
__global__ __launch_bounds__(256) void k_features_f32(
    const float* __restrict__ lc, const float* __restrict__ p,
    const float* __restrict__ other, float* __restrict__ featT) {
  const int b = blockIdx.x;
  const int t = threadIdx.x;
  const float v = lc[b * U + t];
  float a = fabsf(v);
#pragma unroll
  for (int m = 1; m < 64; m <<= 1) a += __shfl_xor(a, m, 64);
  __shared__ float red[4];
  const int lane = t & 63, wv = t >> 6;
  if (lane == 0) red[wv] = a;
  __syncthreads();
  const float l1 = red[0] + red[1] + red[2] + red[3] + EPS_L1;
  featT[(1 + t) * B + b] = v / l1;
  if (t == 0) featT[b] = p[b];
  if (t < F) featT[(1 + U + t) * B + b] = other[b * F + t];
}

__global__ __launch_bounds__(256) void k_gates_f32(
    const float* __restrict__ featT,
    const float* __restrict__ Wi, const float* __restrict__ bi,
    const float* __restrict__ Wo, const float* __restrict__ bo,
    float* __restrict__ ig_n, float* __restrict__ og) {
  constexpr int RB = 16;
  __shared__ float fT[D * RB];
  __shared__ float redb[RB * 4];
  __shared__ float sums[RB];
  const int t = threadIdx.x;
  const int b0 = blockIdx.x * RB;
  for (int i = t; i < D * RB; i += 256) {
    const int k = i >> 4, r = i & 15;
    fT[i] = featT[k * B + b0 + r];
  }
  __syncthreads();
  float ai[RB], ao[RB];
  const float bit = bi[t], bot = bo[t];
#pragma unroll
  for (int r = 0; r < RB; ++r) { ai[r] = bit; ao[r] = bot; }
  for (int k = 0; k < D; ++k) {
    const float wi = Wi[k * U + t];
    const float wo = Wo[k * U + t];
    const float4* fp = (const float4*)(&fT[k * RB]);
#pragma unroll
    for (int q = 0; q < 4; ++q) {
      const float4 f = fp[q];
      const float fr[4] = {f.x, f.y, f.z, f.w};
#pragma unroll
      for (int j = 0; j < 4; ++j) {
        ai[4 * q + j] = fmaf(fr[j], wi, ai[4 * q + j]);
        ao[4 * q + j] = fmaf(fr[j], wo, ao[4 * q + j]);
      }
    }
  }
  float ig[RB], s[RB];
#pragma unroll
  for (int r = 0; r < RB; ++r) {
    ig[r] = 1.0f / (1.0f + expf(-ai[r]));
    s[r] = ig[r];
  }
#pragma unroll
  for (int m = 1; m < 64; m <<= 1) {
#pragma unroll
    for (int r = 0; r < RB; ++r) s[r] += __shfl_xor(s[r], m, 64);
  }
  const int lane = t & 63, wv = t >> 6;
  if (lane == 0) {
#pragma unroll
    for (int r = 0; r < RB; ++r) redb[r * 4 + wv] = s[r];
  }
  __syncthreads();
  if (t < RB) sums[t] = redb[t * 4] + redb[t * 4 + 1] + redb[t * 4 + 2] + redb[t * 4 + 3];
  __syncthreads();
#pragma unroll
  for (int r = 0; r < RB; ++r) {
    ig_n[(b0 + r) * U + t] = ig[r] / sums[r];
    og[(b0 + r) * U + t]   = 1.0f / (1.0f + expf(-ao[r]));
  }
}

__global__ __launch_bounds__(256, 2) void k_heavy_f32(
    const float* __restrict__ featT, const float* __restrict__ lc,
    const float* __restrict__ Wr, const float* __restrict__ br,
    float* __restrict__ cell_sys) {
  constexpr int MT = 64;
  constexpr int UG = 16;
  __shared__ float fT[D * MT];
  __shared__ float rowsum_s[MT];
  __shared__ float alpha_s[MT];
  const int t  = threadIdx.x;
  const int tv = t & 31;
  const int tr = t >> 5;
  const int b0 = blockIdx.x * MT;
  const int u0 = blockIdx.y * UG;
  for (int i = t; i < D * MT; i += 256) {
    const int k = i >> 6, r = i & 63;
    fT[i] = featT[k * B + b0 + r];
  }
  __syncthreads();
  float out[8][8];
#pragma unroll
  for (int j = 0; j < 8; ++j)
#pragma unroll
    for (int i = 0; i < 8; ++i) out[j][i] = 0.0f;
  const float* Fbase = &fT[tr * 8];
  for (int uu = 0; uu < UG; ++uu) {
    const int u = u0 + uu;
    const float* Wbase = Wr + (size_t)u * 256 + tv * 8;
    float cc[8][8];
#pragma unroll
    for (int j = 0; j < 8; ++j)
#pragma unroll
      for (int i = 0; i < 8; ++i) cc[j][i] = 0.0f;
    for (int k = 0; k < D; ++k) {
      const float4* wp = (const float4*)(Wbase + (size_t)k * UU);
      const float4 wa = wp[0], wb = wp[1];
      const float4* fp = (const float4*)(Fbase + k * MT);
      const float4 fa = fp[0], fb = fp[1];
      const float fr[8] = {fa.x, fa.y, fa.z, fa.w, fb.x, fb.y, fb.z, fb.w};
      const float wc[8] = {wa.x, wa.y, wa.z, wa.w, wb.x, wb.y, wb.z, wb.w};
#pragma unroll
      for (int j = 0; j < 8; ++j)
#pragma unroll
        for (int i = 0; i < 8; ++i)
          cc[j][i] = fmaf(fr[j], wc[i], cc[j][i]);
    }
    const float4* bp = (const float4*)(br + (size_t)u * 256 + tv * 8);
    const float4 bb0 = bp[0], bb1 = bp[1];
    const float bc[8] = {bb0.x, bb0.y, bb0.z, bb0.w, bb1.x, bb1.y, bb1.z, bb1.w};
    float ps[8];
#pragma unroll
    for (int j = 0; j < 8; ++j) {
      float sv = 0.0f;
#pragma unroll
      for (int i = 0; i < 8; ++i) {
        cc[j][i] = fmaxf(cc[j][i] + bc[i], 0.0f);
        sv += cc[j][i];
      }
      ps[j] = sv;
    }
#pragma unroll
    for (int m = 1; m < 32; m <<= 1) {
#pragma unroll
      for (int j = 0; j < 8; ++j) ps[j] += __shfl_xor(ps[j], m, 64);
    }
    if (tv == 0) {
#pragma unroll
      for (int j = 0; j < 8; ++j) rowsum_s[tr * 8 + j] = ps[j];
    }
    __syncthreads();
    if (t < MT) alpha_s[t] = lc[(b0 + t) * U + u] / rowsum_s[t];
    __syncthreads();
#pragma unroll
    for (int j = 0; j < 8; ++j) {
      const float a = alpha_s[tr * 8 + j];
#pragma unroll
      for (int i = 0; i < 8; ++i) out[j][i] = fmaf(a, cc[j][i], out[j][i]);
    }
  }
#pragma unroll
  for (int j = 0; j < 8; ++j) {
    const int row = b0 + tr * 8 + j;
#pragma unroll
    for (int i = 0; i < 8; ++i)
      atomicAdd(&cell_sys[row * U + tv * 8 + i], out[j][i]);
  }
}

// ---------------------------------------------------------------- launch
extern "C" void kernel_launch(void* const* d_in, const int* in_sizes, int n_in,
                              void* d_out, int out_size, void* d_ws, size_t ws_size,
                              hipStream_t stream) {
  const float* lc    = (const float*)d_in[0];
  const float* p     = (const float*)d_in[1];
  const float* other = (const float*)d_in[2];
  const float* Wi    = (const float*)d_in[3];
  const float* bi    = (const float*)d_in[4];
  const float* Wr    = (const float*)d_in[5];
  const float* br    = (const float*)d_in[6];
  const float* Wo    = (const float*)d_in[7];
  const float* bo    = (const float*)d_in[8];
  float* out = (float*)d_out;

  const size_t wt_bytes   = (size_t)258 * UIMG;        // 38,043,648
  const size_t feat_bytes = (size_t)B * D * 2;         //    589,824
  const size_t cs_bytes   = (size_t)NBV * 4;           //  1,048,576
  const size_t need = wt_bytes + feat_bytes + cs_bytes;

  if (ws_size >= need) {
    char* wsb = (char*)d_ws;
    short* WtB      = (short*)wsb;
    short* featB    = (short*)(wsb + wt_bytes);
    float* cell_sys = (float*)(wsb + wt_bytes + feat_bytes);

    hipMemsetAsync(cell_sys, 0, cs_bytes, stream);
    k_wt<<<258 * 4, 256, 0, stream>>>(Wr, Wi, Wo, WtB);
    k_featB<<<B, 256, 0, stream>>>(lc, p, other, featB);
    k_gatesM<<<16, 256, 0, stream>>>(featB, WtB, bi, bo, out);
    k_heavyM<<<dim3(16, 32), 256, 0, stream>>>(featB, WtB, lc, br, cell_sys);
    k_final<<<B, 256, 0, stream>>>(cell_sys, p, out);
  } else {
    float* wsf = (float*)d_ws;
    float* featT    = wsf;
    float* cell_sys = wsf + D * B;
    float* ig_n = out;
    float* og   = out + NBV;
    hipMemsetAsync(cell_sys, 0, (size_t)NBV * sizeof(float), stream);
    k_features_f32<<<B, 256, 0, stream>>>(lc, p, other, featT);
    k_gates_f32<<<B / 16, 256, 0, stream>>>(featT, Wi, bi, Wo, bo, ig_n, og);
    k_heavy_f32<<<dim3(16, 16), 256, 0, stream>>>(featT, lc, Wr, br, cell_sys);
    k_final<<<B, 256, 0, stream>>>(cell_sys, p, out);
  }
}

// Round 3
// 234.889 us; speedup vs baseline: 5.6928x; 1.0549x over previous
//
#include <hip/hip_runtime.h>

// MassConservingLSTMCell — round 3: barrier-free K-loop (B global->reg direct),
// coalesced weight transform, fragment-image A staging.
// B=1024, U=256, F=31, D=288 (9 k-chunks of 32).
//
//  k_wtA    : W_r/W_i/W_o f32 -> bf16 fragment images (coalesced via LDS transpose)
//  k_featA  : features -> bf16 MFMA-A fragment image (per 64-row M-block)
//  k_gatesM2: MFMA gates (ig_n, og) stashed in d_out
//  k_heavyM2: fused R-GEMM + relu + row-norm + lc-weighted accumulate -> atomics
//  k_final  : candidate/out/cell combine

#define EPS_L1 1e-7f

constexpr int B = 1024;
constexpr int U = 256;
constexpr int F = 31;
constexpr int D = 1 + U + F;       // 288
constexpr int NBV = B * U;         // 262144
constexpr int NCH = D / 32;        // 9
constexpr int UIMGB = NCH * 16384; // 147456 bytes per u-slice B-image
constexpr size_t WTB_BYTES  = (size_t)258 * UIMGB;  // 38,043,648
constexpr size_t FEAT_BYTES = (size_t)B * D * 2;    // 589,824

typedef float f32x4 __attribute__((ext_vector_type(4)));
typedef short bf16x8 __attribute__((ext_vector_type(8)));

__device__ __forceinline__ unsigned short f2bf(float x) {
  union { float f; unsigned u; } v; v.f = x;
  unsigned r = v.u + 0x7FFFu + ((v.u >> 16) & 1u);
  return (unsigned short)(r >> 16);
}

#define GLDS16(gp, lp)                                                        \
  __builtin_amdgcn_global_load_lds(                                          \
      (const __attribute__((address_space(1))) void*)(gp),                   \
      (__attribute__((address_space(3))) void*)(lp), 16, 0, 0)

// ---------------------------------------------------------------- k_wtA
// One block per (u, c). Phase 1: coalesced read of 32 rows x 256 cols (f32),
// bf16-convert into padded LDS. Phase 2: gather fragment order, write 1KB-
// contiguous regions. Image element (u,c,n0,lane,j) = W[c*32+(lane>>4)*8+j][n0*16+(lane&15)].
__global__ __launch_bounds__(256) void k_wtA(
    const float* __restrict__ Wr, const float* __restrict__ Wi,
    const float* __restrict__ Wo, short* __restrict__ WtB) {
  __shared__ short lds[32 * 258];
  const int t = threadIdx.x;
  const int u = blockIdx.x / 9;
  const int c = blockIdx.x % 9;
  const int k0 = c * 32;

  const float* src; long ld;
  if (u < 256)       { src = Wr + (size_t)u * 256; ld = 65536; }
  else if (u == 256) { src = Wi; ld = 256; }
  else               { src = Wo; ld = 256; }

#pragma unroll
  for (int i = 0; i < 8; ++i) {
    const int r = i * 4 + (t >> 6);
    const int col = (t & 63) * 4;
    const float4 v = *(const float4*)(src + (size_t)(k0 + r) * ld + col);
    const unsigned lo = (unsigned)f2bf(v.x) | ((unsigned)f2bf(v.y) << 16);
    const unsigned hi = (unsigned)f2bf(v.z) | ((unsigned)f2bf(v.w) << 16);
    *(unsigned*)&lds[r * 258 + col]     = lo;
    *(unsigned*)&lds[r * 258 + col + 2] = hi;
  }
  __syncthreads();

#pragma unroll
  for (int i = 0; i < 4; ++i) {
    const int n0 = i * 4 + (t >> 6);
    const int l = t & 63;
    const int g = l >> 4, l15 = l & 15;
    bf16x8 h;
#pragma unroll
    for (int j = 0; j < 8; ++j)
      h[j] = lds[(g * 8 + j) * 258 + n0 * 16 + l15];
    *(bf16x8*)(WtB + (size_t)u * 73728 + (size_t)(c * 16 + n0) * 512 + l * 8) = h;
  }
}

// ---------------------------------------------------------------- k_featA
// 16 blocks x 256. Block handles 64 batch rows: L1 norms, then writes the
// A fragment image: region (c*4+mt), lane l, j -> feat[mt*16+(l&15)][c*32+(l>>4)*8+j].
__global__ __launch_bounds__(256) void k_featA(
    const float* __restrict__ lc, const float* __restrict__ p,
    const float* __restrict__ other, short* __restrict__ featImg) {
  __shared__ float inv_s[64];
  const int t = threadIdx.x, b0 = blockIdx.x * 64;
  const int row = t >> 2, q = t & 3;
  const float4* lp = (const float4*)(lc + (size_t)(b0 + row) * 256 + q * 64);
  float s = 0.f;
#pragma unroll
  for (int j = 0; j < 16; ++j) {
    const float4 v = lp[j];
    s += fabsf(v.x) + fabsf(v.y) + fabsf(v.z) + fabsf(v.w);
  }
  s += __shfl_xor(s, 1, 64);
  s += __shfl_xor(s, 2, 64);
  if (q == 0) inv_s[row] = 1.f / (s + EPS_L1);
  __syncthreads();

#pragma unroll
  for (int i = 0; i < 9; ++i) {
    const int idx = i * 256 + t;
    const int reg = idx >> 6, l = idx & 63;
    const int c = reg >> 2, mt = reg & 3;
    const int lrow = mt * 16 + (l & 15);
    const int grow = b0 + lrow;
    const int k0 = c * 32 + (l >> 4) * 8;
    bf16x8 h;
#pragma unroll
    for (int j = 0; j < 8; ++j) {
      const int k = k0 + j;
      float v;
      if (k == 0) v = p[grow];
      else if (k <= 256) v = lc[(size_t)grow * 256 + (k - 1)] * inv_s[lrow];
      else v = other[(size_t)grow * 31 + (k - 257)];
      h[j] = (short)f2bf(v);
    }
    *(bf16x8*)(featImg + (size_t)blockIdx.x * 18432 + (size_t)reg * 512 + l * 8) = h;
  }
}

// ---------------------------------------------------------------- k_heavyM2
// 512 threads = 8 waves; wave cg covers cols cg*32..+31 (2 n-tiles), all 64 rows
// (4 m-tiles). A via LDS (fragment image, one prologue barrier). B direct
// global->register, distance-2 prefetch, NO barriers in K-loop.
__global__ __launch_bounds__(512, 4) void k_heavyM2(
    const short* __restrict__ featImg, const short* __restrict__ WtB,
    const float* __restrict__ lc, const float* __restrict__ br,
    float* __restrict__ cell_sys) {
  __shared__ short aT[18432];          // 36864 B
  __shared__ float rsum[2][64][12];    // padded: quad-spread banks, 16B aligned
  __shared__ float lcs[2][64];

  const int t = threadIdx.x, lane = t & 63, cg = t >> 6;
  const int quad = lane >> 4, l15 = lane & 15;
  const int bid = blockIdx.x;
  const int ug = (bid & 7) * 4 + ((bid >> 3) >> 4);   // XCD-pinned u-group
  const int mb = (bid >> 3) & 15;
  const int b0 = mb * 64;
  const int u0 = ug * 8;

  // A prologue: linear global->LDS
  {
    const char* gsrc = (const char*)featImg + (size_t)mb * 36864;
    char* ldst = (char*)aT;
#pragma unroll
    for (int i = 0; i < 5; ++i) {
      if (i * 8 + cg < 36) {
        const int off = i * 8192 + t * 16;
        GLDS16(gsrc + off, ldst + off);
      }
    }
  }

  f32x4 acc[4][2], outa[4][2];
#pragma unroll
  for (int mt = 0; mt < 4; ++mt)
#pragma unroll
    for (int n = 0; n < 2; ++n)
#pragma unroll
      for (int r = 0; r < 4; ++r) { acc[mt][n][r] = 0.f; outa[mt][n][r] = 0.f; }

  // B pointer: flat stride 16384B per k-chunk step (9*16384 == UIMGB)
  const char* bptr = (const char*)WtB + (size_t)u0 * UIMGB + cg * 2048 + lane * 16;
  bf16x8 cb0 = *(const bf16x8*)(bptr);
  bf16x8 cb1 = *(const bf16x8*)(bptr + 1024);
  bf16x8 nb0 = *(const bf16x8*)(bptr + 16384);
  bf16x8 nb1 = *(const bf16x8*)(bptr + 16384 + 1024);
  bptr += 32768;

  __syncthreads();   // A ready (drains GLDS)

  float lcreg = 0.f, bv0 = 0.f, bv1 = 0.f;

  for (int uu = 0; uu < 8; ++uu) {
#pragma unroll
    for (int c = 0; c < 9; ++c) {
      const bf16x8 pb0 = *(const bf16x8*)(bptr);
      const bf16x8 pb1 = *(const bf16x8*)(bptr + 1024);
      bptr += 16384;
      if (c == 0) {
        if (t < 64) lcreg = lc[(size_t)(b0 + t) * 256 + u0 + uu];
        bv0 = br[(size_t)(u0 + uu) * 256 + cg * 32 + l15];
        bv1 = br[(size_t)(u0 + uu) * 256 + cg * 32 + 16 + l15];
      }
      const char* ab = (const char*)aT + c * 4096 + lane * 16;
      const bf16x8 a0 = *(const bf16x8*)(ab);
      const bf16x8 a1 = *(const bf16x8*)(ab + 1024);
      const bf16x8 a2 = *(const bf16x8*)(ab + 2048);
      const bf16x8 a3 = *(const bf16x8*)(ab + 3072);
      acc[0][0] = __builtin_amdgcn_mfma_f32_16x16x32_bf16(a0, cb0, acc[0][0], 0, 0, 0);
      acc[0][1] = __builtin_amdgcn_mfma_f32_16x16x32_bf16(a0, cb1, acc[0][1], 0, 0, 0);
      acc[1][0] = __builtin_amdgcn_mfma_f32_16x16x32_bf16(a1, cb0, acc[1][0], 0, 0, 0);
      acc[1][1] = __builtin_amdgcn_mfma_f32_16x16x32_bf16(a1, cb1, acc[1][1], 0, 0, 0);
      acc[2][0] = __builtin_amdgcn_mfma_f32_16x16x32_bf16(a2, cb0, acc[2][0], 0, 0, 0);
      acc[2][1] = __builtin_amdgcn_mfma_f32_16x16x32_bf16(a2, cb1, acc[2][1], 0, 0, 0);
      acc[3][0] = __builtin_amdgcn_mfma_f32_16x16x32_bf16(a3, cb0, acc[3][0], 0, 0, 0);
      acc[3][1] = __builtin_amdgcn_mfma_f32_16x16x32_bf16(a3, cb1, acc[3][1], 0, 0, 0);
      cb0 = nb0; cb1 = nb1; nb0 = pb0; nb1 = pb1;
    }

    // ---- epilogue for u = u0+uu (one barrier, ping-pong LDS)
    {
      const int ub = uu & 1;
      float sm[4][4];
#pragma unroll
      for (int mt = 0; mt < 4; ++mt)
#pragma unroll
        for (int r = 0; r < 4; ++r)
          sm[mt][r] = fmaxf(acc[mt][0][r] + bv0, 0.f) + fmaxf(acc[mt][1][r] + bv1, 0.f);
#pragma unroll
      for (int m = 1; m < 16; m <<= 1)
#pragma unroll
        for (int mt = 0; mt < 4; ++mt)
#pragma unroll
          for (int r = 0; r < 4; ++r)
            sm[mt][r] += __shfl_xor(sm[mt][r], m, 64);
      if (l15 == 0) {
#pragma unroll
        for (int mt = 0; mt < 4; ++mt)
#pragma unroll
          for (int r = 0; r < 4; ++r)
            rsum[ub][mt * 16 + quad * 4 + r][cg] = sm[mt][r];
      }
      if (t < 64) lcs[ub][t] = lcreg;
      __syncthreads();
#pragma unroll
      for (int mt = 0; mt < 4; ++mt)
#pragma unroll
        for (int r = 0; r < 4; ++r) {
          const int row = mt * 16 + quad * 4 + r;
          const float4 ra = *(const float4*)&rsum[ub][row][0];
          const float4 rb = *(const float4*)&rsum[ub][row][4];
          const float rs = ((ra.x + ra.y) + (ra.z + ra.w)) + ((rb.x + rb.y) + (rb.z + rb.w));
          const float alpha = lcs[ub][row] / rs;
          outa[mt][0][r] = fmaf(alpha, fmaxf(acc[mt][0][r] + bv0, 0.f), outa[mt][0][r]);
          outa[mt][1][r] = fmaf(alpha, fmaxf(acc[mt][1][r] + bv1, 0.f), outa[mt][1][r]);
          acc[mt][0][r] = 0.f;
          acc[mt][1][r] = 0.f;
        }
    }
  }

#pragma unroll
  for (int mt = 0; mt < 4; ++mt)
#pragma unroll
    for (int r = 0; r < 4; ++r) {
      const int grow = b0 + mt * 16 + quad * 4 + r;
#pragma unroll
      for (int n = 0; n < 2; ++n)
        atomicAdd(&cell_sys[(size_t)grow * 256 + cg * 32 + n * 16 + l15],
                  outa[mt][n][r]);
    }
}

// ---------------------------------------------------------------- k_gatesM2
// Same frame; u-images 256 (Wi) and 257 (Wo). 16 blocks x 512.
__global__ __launch_bounds__(512, 4) void k_gatesM2(
    const short* __restrict__ featImg, const short* __restrict__ WtB,
    const float* __restrict__ bi, const float* __restrict__ bo,
    float* __restrict__ dout) {
  __shared__ short aT[18432];
  __shared__ float rsum[64][12];

  const int t = threadIdx.x, lane = t & 63, cg = t >> 6;
  const int quad = lane >> 4, l15 = lane & 15;
  const int mb = blockIdx.x, b0 = mb * 64;

  {
    const char* gsrc = (const char*)featImg + (size_t)mb * 36864;
    char* ldst = (char*)aT;
#pragma unroll
    for (int i = 0; i < 5; ++i) {
      if (i * 8 + cg < 36) {
        const int off = i * 8192 + t * 16;
        GLDS16(gsrc + off, ldst + off);
      }
    }
  }

  f32x4 acc[4][2];
#pragma unroll
  for (int mt = 0; mt < 4; ++mt)
#pragma unroll
    for (int n = 0; n < 2; ++n)
#pragma unroll
      for (int r = 0; r < 4; ++r) acc[mt][n][r] = 0.f;

  const char* bptr = (const char*)WtB + (size_t)256 * UIMGB + cg * 2048 + lane * 16;
  bf16x8 cb0 = *(const bf16x8*)(bptr);
  bf16x8 cb1 = *(const bf16x8*)(bptr + 1024);
  bf16x8 nb0 = *(const bf16x8*)(bptr + 16384);
  bf16x8 nb1 = *(const bf16x8*)(bptr + 16384 + 1024);
  bptr += 32768;

  __syncthreads();

#pragma unroll
  for (int g = 0; g < 2; ++g) {
    const float* bias = (g == 0) ? bi : bo;
    const float bv0 = bias[cg * 32 + l15];
    const float bv1 = bias[cg * 32 + 16 + l15];
#pragma unroll
    for (int c = 0; c < 9; ++c) {
      const bf16x8 pb0 = *(const bf16x8*)(bptr);
      const bf16x8 pb1 = *(const bf16x8*)(bptr + 1024);
      bptr += 16384;
      const char* ab = (const char*)aT + c * 4096 + lane * 16;
      const bf16x8 a0 = *(const bf16x8*)(ab);
      const bf16x8 a1 = *(const bf16x8*)(ab + 1024);
      const bf16x8 a2 = *(const bf16x8*)(ab + 2048);
      const bf16x8 a3 = *(const bf16x8*)(ab + 3072);
      acc[0][0] = __builtin_amdgcn_mfma_f32_16x16x32_bf16(a0, cb0, acc[0][0], 0, 0, 0);
      acc[0][1] = __builtin_amdgcn_mfma_f32_16x16x32_bf16(a0, cb1, acc[0][1], 0, 0, 0);
      acc[1][0] = __builtin_amdgcn_mfma_f32_16x16x32_bf16(a1, cb0, acc[1][0], 0, 0, 0);
      acc[1][1] = __builtin_amdgcn_mfma_f32_16x16x32_bf16(a1, cb1, acc[1][1], 0, 0, 0);
      acc[2][0] = __builtin_amdgcn_mfma_f32_16x16x32_bf16(a2, cb0, acc[2][0], 0, 0, 0);
      acc[2][1] = __builtin_amdgcn_mfma_f32_16x16x32_bf16(a2, cb1, acc[2][1], 0, 0, 0);
      acc[3][0] = __builtin_amdgcn_mfma_f32_16x16x32_bf16(a3, cb0, acc[3][0], 0, 0, 0);
      acc[3][1] = __builtin_amdgcn_mfma_f32_16x16x32_bf16(a3, cb1, acc[3][1], 0, 0, 0);
      cb0 = nb0; cb1 = nb1; nb0 = pb0; nb1 = pb1;
    }

    float s0[4][4], s1[4][4];
#pragma unroll
    for (int mt = 0; mt < 4; ++mt)
#pragma unroll
      for (int r = 0; r < 4; ++r) {
        s0[mt][r] = 1.f / (1.f + __expf(-(acc[mt][0][r] + bv0)));
        s1[mt][r] = 1.f / (1.f + __expf(-(acc[mt][1][r] + bv1)));
        acc[mt][0][r] = 0.f;
        acc[mt][1][r] = 0.f;
      }

    if (g == 0) {
      float sm[4][4];
#pragma unroll
      for (int mt = 0; mt < 4; ++mt)
#pragma unroll
        for (int r = 0; r < 4; ++r) sm[mt][r] = s0[mt][r] + s1[mt][r];
#pragma unroll
      for (int m = 1; m < 16; m <<= 1)
#pragma unroll
        for (int mt = 0; mt < 4; ++mt)
#pragma unroll
          for (int r = 0; r < 4; ++r)
            sm[mt][r] += __shfl_xor(sm[mt][r], m, 64);
      if (l15 == 0) {
#pragma unroll
        for (int mt = 0; mt < 4; ++mt)
#pragma unroll
          for (int r = 0; r < 4; ++r)
            rsum[mt * 16 + quad * 4 + r][cg] = sm[mt][r];
      }
      __syncthreads();
#pragma unroll
      for (int mt = 0; mt < 4; ++mt)
#pragma unroll
        for (int r = 0; r < 4; ++r) {
          const int row = mt * 16 + quad * 4 + r;
          const float4 ra = *(const float4*)&rsum[row][0];
          const float4 rb = *(const float4*)&rsum[row][4];
          const float inv = 1.f / (((ra.x + ra.y) + (ra.z + ra.w)) +
                                   ((rb.x + rb.y) + (rb.z + rb.w)));
          dout[(size_t)(b0 + row) * 256 + cg * 32 + l15]      = s0[mt][r] * inv;
          dout[(size_t)(b0 + row) * 256 + cg * 32 + 16 + l15] = s1[mt][r] * inv;
        }
    } else {
#pragma unroll
      for (int mt = 0; mt < 4; ++mt)
#pragma unroll
        for (int r = 0; r < 4; ++r) {
          const int row = mt * 16 + quad * 4 + r;
          dout[(size_t)NBV + (size_t)(b0 + row) * 256 + cg * 32 + l15]      = s0[mt][r];
          dout[(size_t)NBV + (size_t)(b0 + row) * 256 + cg * 32 + 16 + l15] = s1[mt][r];
        }
    }
  }
}

// ---------------------------------------------------------------- k_final
__global__ __launch_bounds__(256) void k_final(
    const float* __restrict__ cell_sys, const float* __restrict__ p,
    float* __restrict__ d_out) {
  const int i = blockIdx.x * 256 + threadIdx.x;
  const float ig = d_out[i];
  const float ogv = d_out[NBV + i];
  const float cand = fmaf(ig, p[i >> 8], cell_sys[i]);
  const float outp = ogv * cand;
  d_out[i] = (1.0f - ogv) * cand;
  d_out[NBV + i] = outp;
}

// ---------------------------------------------------------------- launch
extern "C" void kernel_launch(void* const* d_in, const int* in_sizes, int n_in,
                              void* d_out, int out_size, void* d_ws, size_t ws_size,
                              hipStream_t stream) {
  const float* lc    = (const float*)d_in[0];
  const float* p     = (const float*)d_in[1];
  const float* other = (const float*)d_in[2];
  const float* bi    = (const float*)d_in[4];
  const float* Wr    = (const float*)d_in[5];
  const float* br    = (const float*)d_in[6];
  const float* Wi    = (const float*)d_in[3];
  const float* Wo    = (const float*)d_in[7];
  const float* bo    = (const float*)d_in[8];
  float* out = (float*)d_out;

  char* wsb = (char*)d_ws;
  short* WtB      = (short*)wsb;
  short* featImg  = (short*)(wsb + WTB_BYTES);
  float* cell_sys = (float*)(wsb + WTB_BYTES + FEAT_BYTES);

  hipMemsetAsync(cell_sys, 0, (size_t)NBV * sizeof(float), stream);
  k_wtA<<<258 * 9, 256, 0, stream>>>(Wr, Wi, Wo, WtB);
  k_featA<<<16, 256, 0, stream>>>(lc, p, other, featImg);
  k_gatesM2<<<16, 512, 0, stream>>>(featImg, WtB, bi, bo, out);
  k_heavyM2<<<512, 512, 0, stream>>>(featImg, WtB, lc, br, cell_sys);
  k_final<<<1024, 256, 0, stream>>>(cell_sys, p, out);
}

// Round 4
// 221.713 us; speedup vs baseline: 6.0311x; 1.0594x over previous
//
#include <hip/hip_runtime.h>

// MassConservingLSTMCell — round 4: 128-row blocks (A-dup 8->2), coalesced
// streaming weight transform, 3 launches total.
// B=1024, U=256, F=31, D=288 (9 k-chunks of 32).
//
//  k_prep   : [blocks 0..257] W -> bf16 fragment images (LDS transpose, dbuf)
//             [258..273] features -> bf16 A fragment images (16 x 64-row)
//             [274..281] zero cell_sys
//  k_heavyR4: 256 blocks (8 Mb x 32 ug), 512 thr. A LDS-resident, B global->reg
//             prefetch, barrier-free K-loop, per-u fused relu/rownorm/accum.
//  k_post   : 16 blocks: gates MFMA (ig,og in regs) + final combine.

#define EPS_L1 1e-7f

constexpr int BB  = 1024;
constexpr int U   = 256;
constexpr int F   = 31;
constexpr int D   = 1 + U + F;      // 288
constexpr int NBV = BB * U;         // 262144
constexpr int NCH = D / 32;         // 9
constexpr int UIMGB = NCH * 16384;  // 147456 B per u-slice B-image
constexpr size_t WTB_BYTES  = (size_t)258 * UIMGB;
constexpr size_t FEAT_BYTES = (size_t)BB * D * 2;
constexpr int PITCH = 260;          // LDS transpose pitch (shorts): b64-aligned, 2-way reads

typedef float f32x4 __attribute__((ext_vector_type(4)));
typedef short bf16x8 __attribute__((ext_vector_type(8)));

__device__ __forceinline__ unsigned f2bf(float x) {
  union { float f; unsigned u; } v; v.f = x;
  unsigned r = v.u + 0x7FFFu + ((v.u >> 16) & 1u);
  return r >> 16;
}

#define GLDS16(gp, lp)                                                        \
  __builtin_amdgcn_global_load_lds(                                          \
      (const __attribute__((address_space(1))) void*)(gp),                   \
      (__attribute__((address_space(3))) void*)(lp), 16, 0, 0)

// ---------------------------------------------------------------- k_prep
__global__ __launch_bounds__(256) void k_prep(
    const float* __restrict__ lc, const float* __restrict__ p,
    const float* __restrict__ other,
    const float* __restrict__ Wi, const float* __restrict__ Wr,
    const float* __restrict__ Wo,
    short* __restrict__ WtB, short* __restrict__ featImg,
    float* __restrict__ cell_sys) {
  __shared__ short lds[2][32 * PITCH];
  __shared__ float inv_s[64];
  const int bid = blockIdx.x, t = threadIdx.x;

  if (bid < 258) {
    // ---- weight transform for u-slice `bid`
    const float* src; long ld;
    if (bid < 256)       { src = Wr + (size_t)bid * 256; ld = 65536; }
    else if (bid == 256) { src = Wi; ld = 256; }
    else                 { src = Wo; ld = 256; }
    short* dst = WtB + (size_t)bid * 73728;
    const int lane = t & 63, wave = t >> 6;
    const int g = lane >> 4, l15 = lane & 15;

    for (int c = 0; c < 9; ++c) {
      short* buf = lds[c & 1];
      // phase 1: fully-coalesced reads (1KB per wave-instruction)
#pragma unroll
      for (int i = 0; i < 8; ++i) {
        const int f = i * 256 + t;
        const int row = f >> 6, col4 = f & 63;
        const float4 v = *(const float4*)(src + (size_t)(c * 32 + row) * ld + col4 * 4);
        const unsigned lo = f2bf(v.x) | (f2bf(v.y) << 16);
        const unsigned hi = f2bf(v.z) | (f2bf(v.w) << 16);
        unsigned* wp = (unsigned*)&buf[row * PITCH + col4 * 4];
        wp[0] = lo; wp[1] = hi;
      }
      __syncthreads();
      // phase 2: fragment gather, 1KB-contiguous stores
#pragma unroll
      for (int i = 0; i < 4; ++i) {
        const int n0 = wave * 4 + i;
        bf16x8 h;
#pragma unroll
        for (int j = 0; j < 8; ++j)
          h[j] = buf[(g * 8 + j) * PITCH + n0 * 16 + l15];
        *(bf16x8*)(dst + (size_t)(c * 16 + n0) * 512 + lane * 8) = h;
      }
    }
  } else if (bid < 274) {
    // ---- features -> A fragment image (64-row block mb)
    const int mb = bid - 258;
    const int b0 = mb * 64;
    const int row = t >> 2, q = t & 3;
    const float4* lp = (const float4*)(lc + (size_t)(b0 + row) * 256 + q * 64);
    float s = 0.f;
#pragma unroll
    for (int j = 0; j < 16; ++j) {
      const float4 v = lp[j];
      s += fabsf(v.x) + fabsf(v.y) + fabsf(v.z) + fabsf(v.w);
    }
    s += __shfl_xor(s, 1, 64);
    s += __shfl_xor(s, 2, 64);
    if (q == 0) inv_s[row] = 1.f / (s + EPS_L1);
    __syncthreads();
#pragma unroll
    for (int i = 0; i < 9; ++i) {
      const int idx = i * 256 + t;
      const int reg = idx >> 6, l = idx & 63;
      const int c = reg >> 2, mt = reg & 3;
      const int lrow = mt * 16 + (l & 15);
      const int grow = b0 + lrow;
      const int k0 = c * 32 + (l >> 4) * 8;
      bf16x8 h;
#pragma unroll
      for (int j = 0; j < 8; ++j) {
        const int k = k0 + j;
        float v;
        if (k == 0) v = p[grow];
        else if (k <= 256) v = lc[(size_t)grow * 256 + (k - 1)] * inv_s[lrow];
        else v = other[(size_t)grow * 31 + (k - 257)];
        h[j] = (short)f2bf(v);
      }
      *(bf16x8*)(featImg + (size_t)mb * 18432 + (size_t)reg * 512 + l * 8) = h;
    }
  } else {
    // ---- zero cell_sys (8 blocks x 256 thr x 32 float4)
    float4* cs4 = (float4*)cell_sys;
    const int base = (bid - 274) * 8192 + t;
    const float4 z = {0.f, 0.f, 0.f, 0.f};
#pragma unroll
    for (int k2 = 0; k2 < 32; ++k2) cs4[base + k2 * 256] = z;
  }
}

// ---------------------------------------------------------------- k_heavyR4
// 256 blocks x 512 thr. Block: 128 rows x 256 cols x 8 u. Waves: 4 rg x 2 cg.
// Wave tile: 2 mt x 8 nt (16x16). A LDS-resident (72KB), B global->reg dist-1.
__global__ __launch_bounds__(512, 2) void k_heavyR4(
    const short* __restrict__ featImg, const short* __restrict__ WtB,
    const float* __restrict__ lc, const float* __restrict__ br,
    float* __restrict__ cell_sys) {
  __shared__ short aT[36864];          // 73728 B: [h][c][mt_img][1KB]
  __shared__ float rsum[2][2][128];
  __shared__ float lcs[2][128];

  const int t = threadIdx.x, lane = t & 63, wave = t >> 6;
  const int rg = wave >> 1, cg = wave & 1;
  const int quad = lane >> 4, l15 = lane & 15;
  const int bid = blockIdx.x;
  const int Mb = bid >> 5, ug = bid & 31;   // bid%8 == ug%8 -> ug pinned per XCD
  const int b0 = Mb * 128, u0 = ug * 8;

  // stage A (two consecutive 64-row images, linear)
  {
    const char* gA = (const char*)featImg + (size_t)Mb * 73728;
    char* lA = (char*)aT;
#pragma unroll
    for (int i = 0; i < 9; ++i)
      GLDS16(gA + i * 8192 + t * 16, lA + i * 8192 + t * 16);
  }

  const char* bptr = (const char*)WtB + (size_t)u0 * UIMGB + cg * 8192 + lane * 16;
  bf16x8 bc[8], bn[8];
#pragma unroll
  for (int n = 0; n < 8; ++n) bc[n] = *(const bf16x8*)(bptr + n * 1024);
  bptr += 16384;

  f32x4 acc[2][8], outa[2][8];
#pragma unroll
  for (int mt = 0; mt < 2; ++mt)
#pragma unroll
    for (int n = 0; n < 8; ++n)
#pragma unroll
      for (int r = 0; r < 4; ++r) { acc[mt][n][r] = 0.f; outa[mt][n][r] = 0.f; }

  const char* aB = (const char*)aT + (rg >> 1) * 36864 + (rg & 1) * 2048 + lane * 16;

  __syncthreads();   // A resident

  bf16x8 a0 = *(const bf16x8*)(aB);
  bf16x8 a1 = *(const bf16x8*)(aB + 1024);

  float bv[8], lcv = 0.f;
  int c = 0, u = u0;

  for (int s = 0; s < 72; ++s) {
    // prefetch next-step B (in-bounds through image 256)
#pragma unroll
    for (int n = 0; n < 8; ++n) bn[n] = *(const bf16x8*)(bptr + n * 1024);
    bptr += 16384;
    if (c == 0) {
#pragma unroll
      for (int n = 0; n < 8; ++n)
        bv[n] = br[(size_t)u * 256 + cg * 128 + n * 16 + l15];
      if (t < 128) lcv = lc[(size_t)(b0 + t) * 256 + u];
    }
    const int cn = (c == 8) ? 0 : c + 1;
    const bf16x8 an0 = *(const bf16x8*)(aB + cn * 4096);
    const bf16x8 an1 = *(const bf16x8*)(aB + cn * 4096 + 1024);

#pragma unroll
    for (int n = 0; n < 8; ++n) {
      acc[0][n] = __builtin_amdgcn_mfma_f32_16x16x32_bf16(a0, bc[n], acc[0][n], 0, 0, 0);
      acc[1][n] = __builtin_amdgcn_mfma_f32_16x16x32_bf16(a1, bc[n], acc[1][n], 0, 0, 0);
    }
    a0 = an0; a1 = an1;
#pragma unroll
    for (int n = 0; n < 8; ++n) bc[n] = bn[n];

    if (c == 8) {
      // ---- epilogue for u: bias+relu (into acc), rownorm, weighted accumulate
      const int ub = u & 1;
      float sm[2][4];
#pragma unroll
      for (int mt = 0; mt < 2; ++mt)
#pragma unroll
        for (int r = 0; r < 4; ++r) {
          float sv = 0.f;
#pragma unroll
          for (int n = 0; n < 8; ++n) {
            const float rv = fmaxf(acc[mt][n][r] + bv[n], 0.f);
            acc[mt][n][r] = rv;
            sv += rv;
          }
          sm[mt][r] = sv;
        }
#pragma unroll
      for (int m = 1; m < 16; m <<= 1)
#pragma unroll
        for (int mt = 0; mt < 2; ++mt)
#pragma unroll
          for (int r = 0; r < 4; ++r)
            sm[mt][r] += __shfl_xor(sm[mt][r], m, 64);
      if (l15 == 0) {
#pragma unroll
        for (int mt = 0; mt < 2; ++mt)
#pragma unroll
          for (int r = 0; r < 4; ++r)
            rsum[ub][cg][rg * 32 + mt * 16 + quad * 4 + r] = sm[mt][r];
      }
      if (t < 128) lcs[ub][t] = lcv;
      __syncthreads();
#pragma unroll
      for (int mt = 0; mt < 2; ++mt)
#pragma unroll
        for (int r = 0; r < 4; ++r) {
          const int row = rg * 32 + mt * 16 + quad * 4 + r;
          const float alpha = lcs[ub][row] / (rsum[ub][0][row] + rsum[ub][1][row]);
#pragma unroll
          for (int n = 0; n < 8; ++n) {
            outa[mt][n][r] = fmaf(alpha, acc[mt][n][r], outa[mt][n][r]);
            acc[mt][n][r] = 0.f;
          }
        }
      c = 0; ++u;
    } else {
      ++c;
    }
  }

#pragma unroll
  for (int mt = 0; mt < 2; ++mt)
#pragma unroll
    for (int r = 0; r < 4; ++r) {
      const int grow = b0 + rg * 32 + mt * 16 + quad * 4 + r;
#pragma unroll
      for (int n = 0; n < 8; ++n)
        atomicAdd(&cell_sys[(size_t)grow * 256 + cg * 128 + n * 16 + l15],
                  outa[mt][n][r]);
    }
}

// ---------------------------------------------------------------- k_post
// 16 blocks x 512: gates MFMA (64 rows/block, ig+og kept in regs) + final.
__global__ __launch_bounds__(512, 2) void k_post(
    const short* __restrict__ featImg, const short* __restrict__ WtB,
    const float* __restrict__ bi, const float* __restrict__ bo,
    const float* __restrict__ p, const float* __restrict__ cell_sys,
    float* __restrict__ dout) {
  __shared__ short aT[18432];
  __shared__ float rsum[64][12];
  __shared__ float ps[64];

  const int t = threadIdx.x, lane = t & 63, cg = t >> 6;
  const int quad = lane >> 4, l15 = lane & 15;
  const int mb = blockIdx.x, b0 = mb * 64;

  {
    const char* gsrc = (const char*)featImg + (size_t)mb * 36864;
    char* lbase = (char*)aT;
#pragma unroll
    for (int i = 0; i < 5; ++i) {
      if (i * 8 + cg < 36) {
        const int off = i * 8192 + t * 16;
        GLDS16(gsrc + off, lbase + off);
      }
    }
  }
  if (t < 64) ps[t] = p[b0 + t];

  f32x4 acc[4][2];
#pragma unroll
  for (int mt = 0; mt < 4; ++mt)
#pragma unroll
    for (int n = 0; n < 2; ++n)
#pragma unroll
      for (int r = 0; r < 4; ++r) acc[mt][n][r] = 0.f;

  const char* bptr = (const char*)WtB + (size_t)256 * UIMGB + cg * 2048 + lane * 16;
  bf16x8 cb0 = *(const bf16x8*)(bptr);
  bf16x8 cb1 = *(const bf16x8*)(bptr + 1024);
  bf16x8 nb0 = *(const bf16x8*)(bptr + 16384);
  bf16x8 nb1 = *(const bf16x8*)(bptr + 16384 + 1024);
  bptr += 32768;

  __syncthreads();

  float ig0[4][4], ig1[4][4], og0[4][4], og1[4][4];

#pragma unroll
  for (int g = 0; g < 2; ++g) {
    const float* bias = (g == 0) ? bi : bo;
    const float bv0 = bias[cg * 32 + l15];
    const float bv1 = bias[cg * 32 + 16 + l15];
#pragma unroll
    for (int c = 0; c < 9; ++c) {
      const bf16x8 pb0 = *(const bf16x8*)(bptr);
      const bf16x8 pb1 = *(const bf16x8*)(bptr + 1024);
      bptr += 16384;
      const char* ab = (const char*)aT + c * 4096 + lane * 16;
      const bf16x8 a0 = *(const bf16x8*)(ab);
      const bf16x8 a1 = *(const bf16x8*)(ab + 1024);
      const bf16x8 a2 = *(const bf16x8*)(ab + 2048);
      const bf16x8 a3 = *(const bf16x8*)(ab + 3072);
      acc[0][0] = __builtin_amdgcn_mfma_f32_16x16x32_bf16(a0, cb0, acc[0][0], 0, 0, 0);
      acc[0][1] = __builtin_amdgcn_mfma_f32_16x16x32_bf16(a0, cb1, acc[0][1], 0, 0, 0);
      acc[1][0] = __builtin_amdgcn_mfma_f32_16x16x32_bf16(a1, cb0, acc[1][0], 0, 0, 0);
      acc[1][1] = __builtin_amdgcn_mfma_f32_16x16x32_bf16(a1, cb1, acc[1][1], 0, 0, 0);
      acc[2][0] = __builtin_amdgcn_mfma_f32_16x16x32_bf16(a2, cb0, acc[2][0], 0, 0, 0);
      acc[2][1] = __builtin_amdgcn_mfma_f32_16x16x32_bf16(a2, cb1, acc[2][1], 0, 0, 0);
      acc[3][0] = __builtin_amdgcn_mfma_f32_16x16x32_bf16(a3, cb0, acc[3][0], 0, 0, 0);
      acc[3][1] = __builtin_amdgcn_mfma_f32_16x16x32_bf16(a3, cb1, acc[3][1], 0, 0, 0);
      cb0 = nb0; cb1 = nb1; nb0 = pb0; nb1 = pb1;
    }

#pragma unroll
    for (int mt = 0; mt < 4; ++mt)
#pragma unroll
      for (int r = 0; r < 4; ++r) {
        const float v0 = 1.f / (1.f + __expf(-(acc[mt][0][r] + bv0)));
        const float v1 = 1.f / (1.f + __expf(-(acc[mt][1][r] + bv1)));
        if (g == 0) { ig0[mt][r] = v0; ig1[mt][r] = v1; }
        else        { og0[mt][r] = v0; og1[mt][r] = v1; }
        acc[mt][0][r] = 0.f;
        acc[mt][1][r] = 0.f;
      }

    if (g == 0) {
      float sm[4][4];
#pragma unroll
      for (int mt = 0; mt < 4; ++mt)
#pragma unroll
        for (int r = 0; r < 4; ++r) sm[mt][r] = ig0[mt][r] + ig1[mt][r];
#pragma unroll
      for (int m = 1; m < 16; m <<= 1)
#pragma unroll
        for (int mt = 0; mt < 4; ++mt)
#pragma unroll
          for (int r = 0; r < 4; ++r)
            sm[mt][r] += __shfl_xor(sm[mt][r], m, 64);
      if (l15 == 0) {
#pragma unroll
        for (int mt = 0; mt < 4; ++mt)
#pragma unroll
          for (int r = 0; r < 4; ++r)
            rsum[mt * 16 + quad * 4 + r][cg] = sm[mt][r];
      }
      __syncthreads();
#pragma unroll
      for (int mt = 0; mt < 4; ++mt)
#pragma unroll
        for (int r = 0; r < 4; ++r) {
          const int row = mt * 16 + quad * 4 + r;
          const float4 ra = *(const float4*)&rsum[row][0];
          const float4 rb = *(const float4*)&rsum[row][4];
          const float inv = 1.f / (((ra.x + ra.y) + (ra.z + ra.w)) +
                                   ((rb.x + rb.y) + (rb.z + rb.w)));
          ig0[mt][r] *= inv;
          ig1[mt][r] *= inv;
        }
    }
  }

  // final combine: cand = ig*p + cell_sys; cell=(1-og)cand, out=og*cand
#pragma unroll
  for (int mt = 0; mt < 4; ++mt)
#pragma unroll
    for (int r = 0; r < 4; ++r) {
      const int row = mt * 16 + quad * 4 + r;
      const float pr = ps[row];
      const size_t base = (size_t)(b0 + row) * 256 + cg * 32 + l15;
      {
        const float cand = fmaf(ig0[mt][r], pr, cell_sys[base]);
        dout[base] = (1.f - og0[mt][r]) * cand;
        dout[NBV + base] = og0[mt][r] * cand;
      }
      {
        const float cand = fmaf(ig1[mt][r], pr, cell_sys[base + 16]);
        dout[base + 16] = (1.f - og1[mt][r]) * cand;
        dout[NBV + base + 16] = og1[mt][r] * cand;
      }
    }
}

// ---------------------------------------------------------------- launch
extern "C" void kernel_launch(void* const* d_in, const int* in_sizes, int n_in,
                              void* d_out, int out_size, void* d_ws, size_t ws_size,
                              hipStream_t stream) {
  const float* lc    = (const float*)d_in[0];
  const float* p     = (const float*)d_in[1];
  const float* other = (const float*)d_in[2];
  const float* Wi    = (const float*)d_in[3];
  const float* bi    = (const float*)d_in[4];
  const float* Wr    = (const float*)d_in[5];
  const float* br    = (const float*)d_in[6];
  const float* Wo    = (const float*)d_in[7];
  const float* bo    = (const float*)d_in[8];
  float* out = (float*)d_out;

  char* wsb = (char*)d_ws;
  short* WtB      = (short*)wsb;
  short* featImg  = (short*)(wsb + WTB_BYTES);
  float* cell_sys = (float*)(wsb + WTB_BYTES + FEAT_BYTES);

  k_prep<<<282, 256, 0, stream>>>(lc, p, other, Wi, Wr, Wo, WtB, featImg, cell_sys);
  k_heavyR4<<<256, 512, 0, stream>>>(featImg, WtB, lc, br, cell_sys);
  k_post<<<16, 512, 0, stream>>>(featImg, WtB, bi, bo, p, cell_sys, out);
}

// Round 5
// 220.586 us; speedup vs baseline: 6.0619x; 1.0051x over previous
//
#include <hip/hip_runtime.h>

// MassConservingLSTMCell — round 5: balanced 4x4 wave tile (LDS/TA both ~50%),
// fully-unrolled k-chunk with static register rotation, distance-2 B prefetch.
// B=1024, U=256, F=31, D=288 (9 k-chunks of 32).
//
//  k_prep   : [0..773]  W -> bf16 fragment images (3 chunks/block, LDS transpose)
//             [774..789] features -> bf16 A fragment images (16 x 64-row)
//             [790..797] zero cell_sys
//  k_heavyR5: 256 blocks (8 Mb x 32 ug), 512 thr, 8 waves = 2 rh x 4 cq,
//             wave tile 4mt x 4nt. A LDS-resident, B global->reg dist-2,
//             zero barriers in K-loop, 1 barrier per u-epilogue.
//  k_post   : 16 blocks: gates MFMA (ig,og in regs) + final combine.

#define EPS_L1 1e-7f

constexpr int BB  = 1024;
constexpr int U   = 256;
constexpr int F   = 31;
constexpr int D   = 1 + U + F;      // 288
constexpr int NBV = BB * U;         // 262144
constexpr int NCH = D / 32;         // 9
constexpr int UIMGB = NCH * 16384;  // 147456 B per u-slice B-image
constexpr size_t WTB_BYTES  = (size_t)258 * UIMGB;
constexpr size_t FEAT_BYTES = (size_t)BB * D * 2;
constexpr int PITCH = 260;

typedef float f32x4 __attribute__((ext_vector_type(4)));
typedef short bf16x8 __attribute__((ext_vector_type(8)));

__device__ __forceinline__ unsigned f2bf(float x) {
  union { float f; unsigned u; } v; v.f = x;
  unsigned r = v.u + 0x7FFFu + ((v.u >> 16) & 1u);
  return r >> 16;
}

#define GLDS16(gp, lp)                                                        \
  __builtin_amdgcn_global_load_lds(                                          \
      (const __attribute__((address_space(1))) void*)(gp),                   \
      (__attribute__((address_space(3))) void*)(lp), 16, 0, 0)

#define MFMA16(a, b, c) __builtin_amdgcn_mfma_f32_16x16x32_bf16((a), (b), (c), 0, 0, 0)

// ---------------------------------------------------------------- k_prep
__global__ __launch_bounds__(256) void k_prep(
    const float* __restrict__ lc, const float* __restrict__ p,
    const float* __restrict__ other,
    const float* __restrict__ Wi, const float* __restrict__ Wr,
    const float* __restrict__ Wo,
    short* __restrict__ WtB, short* __restrict__ featImg,
    float* __restrict__ cell_sys) {
  __shared__ short lds[2][32 * PITCH];
  __shared__ float inv_s[64];
  const int bid = blockIdx.x, t = threadIdx.x;

  if (bid < 774) {
    // ---- weight transform: u-slice bid/3, chunks [3*(bid%3), +3)
    const int u = bid / 3, part = bid % 3;
    const float* src; long ld;
    if (u < 256)       { src = Wr + (size_t)u * 256; ld = 65536; }
    else if (u == 256) { src = Wi; ld = 256; }
    else               { src = Wo; ld = 256; }
    short* dst = WtB + (size_t)u * 73728;
    const int lane = t & 63, wave = t >> 6;
    const int g = lane >> 4, l15 = lane & 15;

#pragma unroll
    for (int cc = 0; cc < 3; ++cc) {
      const int c = part * 3 + cc;
      short* buf = lds[cc & 1];
      // phase 1: coalesced reads (1KB per wave-instruction)
#pragma unroll
      for (int i = 0; i < 8; ++i) {
        const int f = i * 256 + t;
        const int row = f >> 6, col4 = f & 63;
        const float4 v = *(const float4*)(src + (size_t)(c * 32 + row) * ld + col4 * 4);
        const unsigned lo = f2bf(v.x) | (f2bf(v.y) << 16);
        const unsigned hi = f2bf(v.z) | (f2bf(v.w) << 16);
        unsigned* wp = (unsigned*)&buf[row * PITCH + col4 * 4];
        wp[0] = lo; wp[1] = hi;
      }
      __syncthreads();
      // phase 2: fragment gather, 1KB-contiguous stores
#pragma unroll
      for (int i = 0; i < 4; ++i) {
        const int n0 = wave * 4 + i;
        bf16x8 h;
#pragma unroll
        for (int j = 0; j < 8; ++j)
          h[j] = buf[(g * 8 + j) * PITCH + n0 * 16 + l15];
        *(bf16x8*)(dst + (size_t)(c * 16 + n0) * 512 + lane * 8) = h;
      }
      __syncthreads();
    }
  } else if (bid < 790) {
    // ---- features -> A fragment image (64-row block mb)
    const int mb = bid - 774;
    const int b0 = mb * 64;
    const int row = t >> 2, q = t & 3;
    const float4* lp = (const float4*)(lc + (size_t)(b0 + row) * 256 + q * 64);
    float s = 0.f;
#pragma unroll
    for (int j = 0; j < 16; ++j) {
      const float4 v = lp[j];
      s += fabsf(v.x) + fabsf(v.y) + fabsf(v.z) + fabsf(v.w);
    }
    s += __shfl_xor(s, 1, 64);
    s += __shfl_xor(s, 2, 64);
    if (q == 0) inv_s[row] = 1.f / (s + EPS_L1);
    __syncthreads();
#pragma unroll
    for (int i = 0; i < 9; ++i) {
      const int idx = i * 256 + t;
      const int reg = idx >> 6, l = idx & 63;
      const int c = reg >> 2, mt = reg & 3;
      const int lrow = mt * 16 + (l & 15);
      const int grow = b0 + lrow;
      const int k0 = c * 32 + (l >> 4) * 8;
      bf16x8 h;
#pragma unroll
      for (int j = 0; j < 8; ++j) {
        const int k = k0 + j;
        float v;
        if (k == 0) v = p[grow];
        else if (k <= 256) v = lc[(size_t)grow * 256 + (k - 1)] * inv_s[lrow];
        else v = other[(size_t)grow * 31 + (k - 257)];
        h[j] = (short)f2bf(v);
      }
      *(bf16x8*)(featImg + (size_t)mb * 18432 + (size_t)reg * 512 + l * 8) = h;
    }
  } else {
    // ---- zero cell_sys
    float4* cs4 = (float4*)cell_sys;
    const int base = (bid - 790) * 8192 + t;
    const float4 z = {0.f, 0.f, 0.f, 0.f};
#pragma unroll
    for (int k2 = 0; k2 < 32; ++k2) cs4[base + k2 * 256] = z;
  }
}

// ---------------------------------------------------------------- k_heavyR5
__global__ __launch_bounds__(512, 2) void k_heavyR5(
    const short* __restrict__ featImg, const short* __restrict__ WtB,
    const float* __restrict__ lc, const float* __restrict__ br,
    float* __restrict__ cell_sys) {
  __shared__ short aT[36864];          // 73728 B: [rh][c][mt][1KB]
  __shared__ float rsum[2][128][4];    // [par][row][cq]
  __shared__ float lcs[2][128];

  const int t = threadIdx.x, lane = t & 63, wave = t >> 6;
  const int cq = wave & 3, rh = wave >> 2;
  const int quad = lane >> 4, l15 = lane & 15;
  const int bid = blockIdx.x;
  const int Mb = bid >> 5, ug = bid & 31;   // ug%8 = XCD pin
  const int b0 = Mb * 128, u0 = ug * 8;

  // stage A (two 64-row images, linear)
  {
    const char* gA = (const char*)featImg + (size_t)Mb * 73728;
    char* lA = (char*)aT;
#pragma unroll
    for (int i = 0; i < 9; ++i)
      GLDS16(gA + i * 8192 + t * 16, lA + i * 8192 + t * 16);
  }

  const char* aB = (const char*)aT + rh * 36864 + lane * 16;   // + c*4096 + m*1024
  const char* bB = (const char*)WtB + (size_t)u0 * UIMGB + cq * 4096 + lane * 16;

  f32x4 acc[4][4], outa[4][4];
#pragma unroll
  for (int m = 0; m < 4; ++m)
#pragma unroll
    for (int n = 0; n < 4; ++n)
#pragma unroll
      for (int r = 0; r < 4; ++r) { acc[m][n][r] = 0.f; outa[m][n][r] = 0.f; }

  // B distance-2 prefetch: 3-slot static rotation
  bf16x8 bfr[3][4];
#pragma unroll
  for (int n = 0; n < 4; ++n) bfr[0][n] = *(const bf16x8*)(bB + n * 1024);
#pragma unroll
  for (int n = 0; n < 4; ++n) bfr[1][n] = *(const bf16x8*)(bB + 16384 + n * 1024);

  __syncthreads();   // A resident (drains GLDS + B prefetch harmlessly)

  // A distance-1 prefetch: 2-slot rotation; afr[0] = A[0]
  bf16x8 afr[2][4];
#pragma unroll
  for (int m = 0; m < 4; ++m) afr[0][m] = *(const bf16x8*)(aB + m * 1024);

  for (int uu = 0; uu < 8; ++uu) {
    const int u = u0 + uu;
    float bv[4];

#pragma unroll
    for (int c = 0; c < 9; ++c) {
      if (c == 0) {
#pragma unroll
        for (int n = 0; n < 4; ++n)
          bv[n] = br[(size_t)u * 256 + cq * 64 + n * 16 + l15];
        if (t < 128) lcs[uu & 1][t] = lc[(size_t)(b0 + t) * 256 + u];
      }
      // B prefetch c+2 (flat; crosses into u+1's image at c>=7)
#pragma unroll
      for (int n = 0; n < 4; ++n)
        bfr[(c + 2) % 3][n] = *(const bf16x8*)(bB + (c + 2) * 16384 + n * 1024);
      // A prefetch c+1 (skip at c==8; epilogue reloads A[0])
      if (c < 8) {
#pragma unroll
        for (int m = 0; m < 4; ++m)
          afr[(c + 1) & 1][m] = *(const bf16x8*)(aB + (c + 1) * 4096 + m * 1024);
      }
#pragma unroll
      for (int m = 0; m < 4; ++m)
#pragma unroll
        for (int n = 0; n < 4; ++n)
          acc[m][n] = MFMA16(afr[c & 1][m], bfr[c % 3][n], acc[m][n]);
    }
    bB += UIMGB;

    // issue next-u A[0] reload early (content static; hidden under epilogue)
#pragma unroll
    for (int m = 0; m < 4; ++m) afr[0][m] = *(const bf16x8*)(aB + m * 1024);

    // ---- epilogue for u: bias+relu (into acc), cross-wave rownorm, accumulate
    const int ub = uu & 1;
    float sm[4][4];
#pragma unroll
    for (int m = 0; m < 4; ++m)
#pragma unroll
      for (int r = 0; r < 4; ++r) {
        float sv = 0.f;
#pragma unroll
        for (int n = 0; n < 4; ++n) {
          const float rv = fmaxf(acc[m][n][r] + bv[n], 0.f);
          acc[m][n][r] = rv;
          sv += rv;
        }
        sm[m][r] = sv;
      }
#pragma unroll
    for (int msk = 1; msk < 16; msk <<= 1)
#pragma unroll
      for (int m = 0; m < 4; ++m)
#pragma unroll
        for (int r = 0; r < 4; ++r)
          sm[m][r] += __shfl_xor(sm[m][r], msk, 64);
    if (l15 == 0) {
#pragma unroll
      for (int m = 0; m < 4; ++m)
#pragma unroll
        for (int r = 0; r < 4; ++r)
          rsum[ub][rh * 64 + m * 16 + quad * 4 + r][cq] = sm[m][r];
    }
    __syncthreads();
#pragma unroll
    for (int m = 0; m < 4; ++m)
#pragma unroll
      for (int r = 0; r < 4; ++r) {
        const int row = rh * 64 + m * 16 + quad * 4 + r;
        const float4 rv = *(const float4*)&rsum[ub][row][0];
        const float tot = (rv.x + rv.y) + (rv.z + rv.w);
        const float alpha = lcs[ub][row] * __builtin_amdgcn_rcpf(tot);
#pragma unroll
        for (int n = 0; n < 4; ++n) {
          outa[m][n][r] = fmaf(alpha, acc[m][n][r], outa[m][n][r]);
          acc[m][n][r] = 0.f;
        }
      }
  }

#pragma unroll
  for (int m = 0; m < 4; ++m)
#pragma unroll
    for (int r = 0; r < 4; ++r) {
      const int grow = b0 + rh * 64 + m * 16 + quad * 4 + r;
#pragma unroll
      for (int n = 0; n < 4; ++n)
        atomicAdd(&cell_sys[(size_t)grow * 256 + cq * 64 + n * 16 + l15],
                  outa[m][n][r]);
    }
}

// ---------------------------------------------------------------- k_post
// 16 blocks x 512: gates MFMA (64 rows/block, ig+og in regs) + final combine.
__global__ __launch_bounds__(512, 2) void k_post(
    const short* __restrict__ featImg, const short* __restrict__ WtB,
    const float* __restrict__ bi, const float* __restrict__ bo,
    const float* __restrict__ p, const float* __restrict__ cell_sys,
    float* __restrict__ dout) {
  __shared__ short aT[18432];
  __shared__ float rsum[64][12];
  __shared__ float ps[64];

  const int t = threadIdx.x, lane = t & 63, cg = t >> 6;
  const int quad = lane >> 4, l15 = lane & 15;
  const int mb = blockIdx.x, b0 = mb * 64;

  {
    const char* gsrc = (const char*)featImg + (size_t)mb * 36864;
    char* lbase = (char*)aT;
#pragma unroll
    for (int i = 0; i < 5; ++i) {
      if (i * 8 + cg < 36) {
        const int off = i * 8192 + t * 16;
        GLDS16(gsrc + off, lbase + off);
      }
    }
  }
  if (t < 64) ps[t] = p[b0 + t];

  f32x4 acc[4][2];
#pragma unroll
  for (int mt = 0; mt < 4; ++mt)
#pragma unroll
    for (int n = 0; n < 2; ++n)
#pragma unroll
      for (int r = 0; r < 4; ++r) acc[mt][n][r] = 0.f;

  const char* bptr = (const char*)WtB + (size_t)256 * UIMGB + cg * 2048 + lane * 16;
  bf16x8 cb0 = *(const bf16x8*)(bptr);
  bf16x8 cb1 = *(const bf16x8*)(bptr + 1024);
  bf16x8 nb0 = *(const bf16x8*)(bptr + 16384);
  bf16x8 nb1 = *(const bf16x8*)(bptr + 16384 + 1024);
  bptr += 32768;

  __syncthreads();

  float ig0[4][4], ig1[4][4], og0[4][4], og1[4][4];

#pragma unroll
  for (int g = 0; g < 2; ++g) {
    const float* bias = (g == 0) ? bi : bo;
    const float bv0 = bias[cg * 32 + l15];
    const float bv1 = bias[cg * 32 + 16 + l15];
#pragma unroll
    for (int c = 0; c < 9; ++c) {
      const bf16x8 pb0 = *(const bf16x8*)(bptr);
      const bf16x8 pb1 = *(const bf16x8*)(bptr + 1024);
      bptr += 16384;
      const char* ab = (const char*)aT + c * 4096 + lane * 16;
      const bf16x8 a0 = *(const bf16x8*)(ab);
      const bf16x8 a1 = *(const bf16x8*)(ab + 1024);
      const bf16x8 a2 = *(const bf16x8*)(ab + 2048);
      const bf16x8 a3 = *(const bf16x8*)(ab + 3072);
      acc[0][0] = MFMA16(a0, cb0, acc[0][0]);
      acc[0][1] = MFMA16(a0, cb1, acc[0][1]);
      acc[1][0] = MFMA16(a1, cb0, acc[1][0]);
      acc[1][1] = MFMA16(a1, cb1, acc[1][1]);
      acc[2][0] = MFMA16(a2, cb0, acc[2][0]);
      acc[2][1] = MFMA16(a2, cb1, acc[2][1]);
      acc[3][0] = MFMA16(a3, cb0, acc[3][0]);
      acc[3][1] = MFMA16(a3, cb1, acc[3][1]);
      cb0 = nb0; cb1 = nb1; nb0 = pb0; nb1 = pb1;
    }

#pragma unroll
    for (int mt = 0; mt < 4; ++mt)
#pragma unroll
      for (int r = 0; r < 4; ++r) {
        const float v0 = 1.f / (1.f + __expf(-(acc[mt][0][r] + bv0)));
        const float v1 = 1.f / (1.f + __expf(-(acc[mt][1][r] + bv1)));
        if (g == 0) { ig0[mt][r] = v0; ig1[mt][r] = v1; }
        else        { og0[mt][r] = v0; og1[mt][r] = v1; }
        acc[mt][0][r] = 0.f;
        acc[mt][1][r] = 0.f;
      }

    if (g == 0) {
      float sm[4][4];
#pragma unroll
      for (int mt = 0; mt < 4; ++mt)
#pragma unroll
        for (int r = 0; r < 4; ++r) sm[mt][r] = ig0[mt][r] + ig1[mt][r];
#pragma unroll
      for (int msk = 1; msk < 16; msk <<= 1)
#pragma unroll
        for (int mt = 0; mt < 4; ++mt)
#pragma unroll
          for (int r = 0; r < 4; ++r)
            sm[mt][r] += __shfl_xor(sm[mt][r], msk, 64);
      if (l15 == 0) {
#pragma unroll
        for (int mt = 0; mt < 4; ++mt)
#pragma unroll
          for (int r = 0; r < 4; ++r)
            rsum[mt * 16 + quad * 4 + r][cg] = sm[mt][r];
      }
      __syncthreads();
#pragma unroll
      for (int mt = 0; mt < 4; ++mt)
#pragma unroll
        for (int r = 0; r < 4; ++r) {
          const int row = mt * 16 + quad * 4 + r;
          const float4 ra = *(const float4*)&rsum[row][0];
          const float4 rb = *(const float4*)&rsum[row][4];
          const float inv = 1.f / (((ra.x + ra.y) + (ra.z + ra.w)) +
                                   ((rb.x + rb.y) + (rb.z + rb.w)));
          ig0[mt][r] *= inv;
          ig1[mt][r] *= inv;
        }
    }
  }

#pragma unroll
  for (int mt = 0; mt < 4; ++mt)
#pragma unroll
    for (int r = 0; r < 4; ++r) {
      const int row = mt * 16 + quad * 4 + r;
      const float pr = ps[row];
      const size_t base = (size_t)(b0 + row) * 256 + cg * 32 + l15;
      {
        const float cand = fmaf(ig0[mt][r], pr, cell_sys[base]);
        dout[base] = (1.f - og0[mt][r]) * cand;
        dout[NBV + base] = og0[mt][r] * cand;
      }
      {
        const float cand = fmaf(ig1[mt][r], pr, cell_sys[base + 16]);
        dout[base + 16] = (1.f - og1[mt][r]) * cand;
        dout[NBV + base + 16] = og1[mt][r] * cand;
      }
    }
}

// ---------------------------------------------------------------- launch
extern "C" void kernel_launch(void* const* d_in, const int* in_sizes, int n_in,
                              void* d_out, int out_size, void* d_ws, size_t ws_size,
                              hipStream_t stream) {
  const float* lc    = (const float*)d_in[0];
  const float* p     = (const float*)d_in[1];
  const float* other = (const float*)d_in[2];
  const float* Wi    = (const float*)d_in[3];
  const float* bi    = (const float*)d_in[4];
  const float* Wr    = (const float*)d_in[5];
  const float* br    = (const float*)d_in[6];
  const float* Wo    = (const float*)d_in[7];
  const float* bo    = (const float*)d_in[8];
  float* out = (float*)d_out;

  char* wsb = (char*)d_ws;
  short* WtB      = (short*)wsb;
  short* featImg  = (short*)(wsb + WTB_BYTES);
  float* cell_sys = (float*)(wsb + WTB_BYTES + FEAT_BYTES);

  k_prep<<<798, 256, 0, stream>>>(lc, p, other, Wi, Wr, Wo, WtB, featImg, cell_sys);
  k_heavyR5<<<256, 512, 0, stream>>>(featImg, WtB, lc, br, cell_sys);
  k_post<<<16, 512, 0, stream>>>(featImg, WtB, bi, bo, p, cell_sys, out);
}